// Round 2
// baseline (574.073 us; speedup 1.0000x reference)
//
#include <hip/hip_runtime.h>
#include <hip/hip_bf16.h>
#include <cstdint>
#include <cstddef>

// ---------- types ----------
typedef __bf16 bf16_t;
typedef __bf16 bf16x8 __attribute__((ext_vector_type(8)));
typedef __bf16 bf16x4 __attribute__((ext_vector_type(4)));
typedef float  f32x4  __attribute__((ext_vector_type(4)));

#define DIM    1024
#define NCOEF  8
#define KTOT   (DIM + DIM * NCOEF)   // 9216
#define NKNOT  12
#define BATCH  8192
#define LN_EPS 1e-5f

// ---------- device helpers ----------
__device__ __forceinline__ float gelu_exact(float x) {
    return 0.5f * x * (1.0f + erff(x * 0.70710678118654752440f));
}

__device__ __forceinline__ void gl_lds16(const void* g, void* l) {
    __builtin_amdgcn_global_load_lds(
        (const __attribute__((address_space(1))) unsigned int*)(uintptr_t)g,
        (__attribute__((address_space(3))) unsigned int*)(uintptr_t)l, 16, 0, 0);
}

__device__ __forceinline__ uint64_t pack4bf(float a, float b, float c, float d) {
    union { bf16_t h[4]; uint64_t q; } u;
    u.h[0] = (bf16_t)a; u.h[1] = (bf16_t)b; u.h[2] = (bf16_t)c; u.h[3] = (bf16_t)d;
    return u.q;
}

// Uniform cubic B-spline: 8 bf16 bases of one feature as 16 bytes (lo,hi).
__device__ __forceinline__ void spline8(float x, float g0, float invh,
                                        uint64_t& lo, uint64_t& hi) {
    float u = (x - g0) * invh;
    float jf = floorf(u);
    int j = (int)jf;
    float f = u - jf;
    float f2 = f * f, f3 = f2 * f;
    float om = 1.0f - f, om2 = om * om;
    float w0 = om2 * om * (1.0f / 6.0f);
    float w3 = f3 * (1.0f / 6.0f);
    float w1 = fmaf(0.5f, f3, 2.0f / 3.0f) - f2;
    float w2 = 1.0f - w0 - w1 - w3;
    uint64_t W64 = pack4bf(w0, w1, w2, w3);
    if (!(u >= 0.0f && u < 11.0f)) W64 = 0;
    int sh = (j - 3) * 16;
    if (sh >= 0) {
        int s = sh & 63;
        uint64_t loW = W64 << s;
        uint64_t hiW = s ? (W64 >> (64 - s)) : 0ull;
        lo = (sh < 64) ? loW : 0ull;
        hi = (sh < 64) ? hiW : loW;
    } else {
        lo = W64 >> (-sh);
        hi = 0ull;
    }
}

// ---------- W pack: [base_w | spline_w] f32 -> bf16, K-packed ----------
__global__ void pack_w(const float* __restrict__ bw, const float* __restrict__ sw,
                       bf16_t* __restrict__ W) {
    int idx = blockIdx.x * 256 + threadIdx.x;      // (layer,o,j)
    bf16_t* wrow = W + (size_t)(idx >> 10) * KTOT;
    int j = idx & 1023;
    wrow[j] = (bf16_t)bw[idx];
    const float4* sp = (const float4*)(sw + (size_t)idx * NCOEF);
    float4 s0 = sp[0], s1 = sp[1];
    bf16x8 v;
    v[0] = (bf16_t)s0.x; v[1] = (bf16_t)s0.y; v[2] = (bf16_t)s0.z; v[3] = (bf16_t)s0.w;
    v[4] = (bf16_t)s1.x; v[5] = (bf16_t)s1.y; v[6] = (bf16_t)s1.z; v[7] = (bf16_t)s1.w;
    *(bf16x8*)(wrow + DIM + j * NCOEF) = v;
}

// ---------- layer-0 A build: A[row] = [gelu(x) bf16 x1024 | bases bf16 x8192] ----------
__global__ void prep_A(const float* __restrict__ x, bf16_t* __restrict__ A,
                       const float* __restrict__ gp) {
    const int row = blockIdx.x, t = threadIdx.x;   // 256 threads, 4 features each
    const float g0 = gp[0];
    const float invh = 1.0f / (gp[1] - gp[0]);
    f32x4 v = *(const f32x4*)(x + (size_t)row * DIM + t * 4);
    bf16_t* Ar = A + (size_t)row * KTOT;
    bf16x4 ge;
#pragma unroll
    for (int k = 0; k < 4; k++) ge[k] = (bf16_t)gelu_exact(v[k]);
    *(bf16x4*)(Ar + t * 4) = ge;
#pragma unroll
    for (int k = 0; k < 4; k++) {
        uint64_t lo, hi;
        union { uint64_t u[2]; uint4 q; } o;
        spline8(v[k], g0, invh, lo, hi);
        o.u[0] = lo; o.u[1] = hi;
        *(uint4*)(Ar + DIM + (t * 4 + k) * NCOEF) = o.q;
    }
}

// =====================================================================
// Pure dense GEMM: C[ks] += A[256 rows] x W^T[256 cols], K staged via
// global_load_lds. BM=BN=256, BK=32, 8 waves, 4-slot LDS rotation,
// counted vmcnt(8) (2 tiles in flight), 1 barrier/tile, setprio on MFMA.
// Chunk-XOR swizzle: physical 16B chunk = logical ^ ((row>>1)&3).
// =====================================================================

#define STAGE(T, S) { \
    const size_t ko_ = (size_t)(T) * 32; \
    gl_lds16(Ag0 + ko_, ldsA + (S) * 8192 + tid * 8); \
    gl_lds16(Ag1 + ko_, ldsA + (S) * 8192 + 4096 + tid * 8); \
    gl_lds16(Bg0 + ko_, ldsB + (S) * 8192 + tid * 8); \
    gl_lds16(Bg1 + ko_, ldsB + (S) * 8192 + 4096 + tid * 8); }

#define MF_ROW(I, A_) \
    acc[I][0] = __builtin_amdgcn_mfma_f32_16x16x32_bf16(A_, b0_, acc[I][0], 0, 0, 0); \
    acc[I][1] = __builtin_amdgcn_mfma_f32_16x16x32_bf16(A_, b1_, acc[I][1], 0, 0, 0); \
    acc[I][2] = __builtin_amdgcn_mfma_f32_16x16x32_bf16(A_, b2_, acc[I][2], 0, 0, 0); \
    acc[I][3] = __builtin_amdgcn_mfma_f32_16x16x32_bf16(A_, b3_, acc[I][3], 0, 0, 0);

#define TILE_COMPUTE(S) { \
    const bf16_t* Bb_ = ldsB + (S) * 8192 + bOff; \
    bf16x8 b0_ = *(const bf16x8*)(Bb_),        b1_ = *(const bf16x8*)(Bb_ + 512), \
           b2_ = *(const bf16x8*)(Bb_ + 1024), b3_ = *(const bf16x8*)(Bb_ + 1536); \
    const bf16_t* Ab_ = ldsA + (S) * 8192 + aOff; \
    { bf16x8 a0_ = *(const bf16x8*)(Ab_),        a1_ = *(const bf16x8*)(Ab_ + 512), \
             a2_ = *(const bf16x8*)(Ab_ + 1024), a3_ = *(const bf16x8*)(Ab_ + 1536); \
      __builtin_amdgcn_s_setprio(1); \
      MF_ROW(0, a0_) MF_ROW(1, a1_) MF_ROW(2, a2_) MF_ROW(3, a3_) \
      __builtin_amdgcn_s_setprio(0); } \
    { bf16x8 a4_ = *(const bf16x8*)(Ab_ + 2048), a5_ = *(const bf16x8*)(Ab_ + 2560), \
             a6_ = *(const bf16x8*)(Ab_ + 3072), a7_ = *(const bf16x8*)(Ab_ + 3584); \
      __builtin_amdgcn_s_setprio(1); \
      MF_ROW(4, a4_) MF_ROW(5, a5_) MF_ROW(6, a6_) MF_ROW(7, a7_) \
      __builtin_amdgcn_s_setprio(0); } }

#define BAR() { __builtin_amdgcn_s_barrier(); asm volatile("" ::: "memory"); }

#define TILE_MAIN(T, S, SP) { \
    STAGE((T) + 2, SP) \
    asm volatile("s_waitcnt vmcnt(8)" ::: "memory"); \
    BAR() \
    TILE_COMPUTE(S) }

template<int NTK>
__global__ __launch_bounds__(512, 2) void gemm_ab(
    const bf16_t* __restrict__ A,      // [rows, 9216] bf16
    const bf16_t* __restrict__ W,      // [1024, 9216] bf16
    float* __restrict__ C,             // [ksplit, rows, 1024] f32 partials
    int mmask, int mshift, int rows) {
    __shared__ __align__(16) bf16_t lds[65536];    // 128 KB
    bf16_t* __restrict__ ldsA = lds;
    bf16_t* __restrict__ ldsB = lds + 32768;

    const int tid = threadIdx.x;
    const int l = tid & 63, wv = tid >> 6;
    const int wm = wv >> 2, wn = wv & 3;           // 2M x 4N waves, 128x64 each

    // XCD-aware swizzle (grid always divisible by 8)
    const int chunk = gridDim.x >> 3;
    const int bid = blockIdx.x;
    const int wg = (bid & 7) * chunk + (bid >> 3);
    const int bm = wg & mmask;
    const int bn = (wg >> mshift) & 3;
    const int ks = wg >> (mshift + 2);
    const int row0 = bm << 8, col0 = bn << 8;
    const int koff0 = ks * (NTK * 32);

    // staging: thread covers rows srow, srow+128; source pre-swizzled by chunk
    const int srow = tid >> 2;
    const int slc = (tid & 3) ^ ((srow >> 1) & 3);
    const bf16_t* __restrict__ Ag0 = A + (size_t)(row0 + srow) * KTOT + koff0 + slc * 8;
    const bf16_t* __restrict__ Ag1 = Ag0 + (size_t)128 * KTOT;
    const bf16_t* __restrict__ Bg0 = W + (size_t)(col0 + srow) * KTOT + koff0 + slc * 8;
    const bf16_t* __restrict__ Bg1 = Bg0 + (size_t)128 * KTOT;

    // fragment-read offsets; physical chunk = logical(l>>4) ^ ((row>>1)&3)
    const int l15 = l & 15;
    const int pc = (l >> 4) ^ ((l15 >> 1) & 3);
    const int aOff = (wm * 128 + l15) * 32 + pc * 8;
    const int bOff = (wn * 64 + l15) * 32 + pc * 8;

    f32x4 acc[8][4] = {};

    STAGE(0, 0)
    STAGE(1, 1)
#pragma unroll 1
    for (int t = 0; t < NTK - 4; t += 4) {
        TILE_MAIN(t,     0, 2)
        TILE_MAIN(t + 1, 1, 3)
        TILE_MAIN(t + 2, 2, 0)
        TILE_MAIN(t + 3, 3, 1)
    }
    TILE_MAIN(NTK - 4, 0, 2)
    TILE_MAIN(NTK - 3, 1, 3)
    asm volatile("s_waitcnt vmcnt(4)" ::: "memory");
    BAR()
    TILE_COMPUTE(2)
    asm volatile("s_waitcnt vmcnt(0)" ::: "memory");
    BAR()
    TILE_COMPUTE(3)

    float* __restrict__ Cp = C + (size_t)ks * rows * DIM;
    const int r0 = row0 + wm * 128 + (l >> 4) * 4;
    const int c0 = col0 + wn * 64 + l15;
#pragma unroll
    for (int i = 0; i < 8; i++)
#pragma unroll
        for (int j = 0; j < 4; j++)
#pragma unroll
            for (int r = 0; r < 4; r++)
                Cp[(size_t)(r0 + i * 16 + r) * DIM + c0 + j * 16] = acc[i][j][r];
}

// ---------- LN + PReLU over summed partials -> next-layer A (gelu + bases) ----------
__global__ void ln_mid_A(const float* __restrict__ h, int rows, int ksplit,
                         const float* __restrict__ g_ln, const float* __restrict__ b_ln,
                         const float* __restrict__ pa, bf16_t* __restrict__ A,
                         const float* __restrict__ gp) {
    const int row = blockIdx.x, tid = threadIdx.x;
    const int w = tid >> 6, l = tid & 63;
    f32x4 v = {0.0f, 0.0f, 0.0f, 0.0f};
    for (int ks = 0; ks < ksplit; ks++)
        v += *(const f32x4*)(h + ((size_t)ks * rows + row) * DIM + tid * 4);
    float s = v[0] + v[1] + v[2] + v[3];
    float q = v[0] * v[0] + v[1] * v[1] + v[2] * v[2] + v[3] * v[3];
#pragma unroll
    for (int o = 32; o > 0; o >>= 1) { s += __shfl_xor(s, o); q += __shfl_xor(q, o); }
    __shared__ float rs[4], rq[4];
    if (l == 0) { rs[w] = s; rq[w] = q; }
    __syncthreads();
    s = rs[0] + rs[1] + rs[2] + rs[3];
    q = rq[0] + rq[1] + rq[2] + rq[3];
    float mean = s * (1.0f / DIM);
    float var = q * (1.0f / DIM) - mean * mean;
    float rstd = rsqrtf(var + LN_EPS);
    float a = pa[0];
    const float g0 = gp[0];
    const float invh = 1.0f / (gp[1] - gp[0]);
    bf16_t* Ar = A + (size_t)row * KTOT;
    bf16x4 ge;
#pragma unroll
    for (int c = 0; c < 4; c++) {
        int col = tid * 4 + c;
        float yv = (v[c] - mean) * rstd * g_ln[col] + b_ln[col];
        yv = (yv >= 0.0f) ? yv : a * yv;
        ge[c] = (bf16_t)gelu_exact(yv);
        uint64_t lo, hi;
        union { uint64_t u[2]; uint4 qv; } o;
        spline8(yv, g0, invh, lo, hi);
        o.u[0] = lo; o.u[1] = hi;
        *(uint4*)(Ar + DIM + (size_t)col * NCOEF) = o.qv;
    }
    *(bf16x4*)(Ar + tid * 4) = ge;
}

// ---------- final LN + PReLU -> f32 out ----------
__global__ void ln_out(const float* __restrict__ h, int rows, int ksplit,
                       const float* __restrict__ g_ln, const float* __restrict__ b_ln,
                       const float* __restrict__ pa, float* __restrict__ out) {
    const int row = blockIdx.x, tid = threadIdx.x;
    const int w = tid >> 6, l = tid & 63;
    f32x4 v = {0.0f, 0.0f, 0.0f, 0.0f};
    for (int ks = 0; ks < ksplit; ks++)
        v += *(const f32x4*)(h + ((size_t)ks * rows + row) * DIM + tid * 4);
    float s = v[0] + v[1] + v[2] + v[3];
    float q = v[0] * v[0] + v[1] * v[1] + v[2] * v[2] + v[3] * v[3];
#pragma unroll
    for (int o = 32; o > 0; o >>= 1) { s += __shfl_xor(s, o); q += __shfl_xor(q, o); }
    __shared__ float rs[4], rq[4];
    if (l == 0) { rs[w] = s; rq[w] = q; }
    __syncthreads();
    s = rs[0] + rs[1] + rs[2] + rs[3];
    q = rq[0] + rq[1] + rq[2] + rq[3];
    float mean = s * (1.0f / DIM);
    float var = q * (1.0f / DIM) - mean * mean;
    float rstd = rsqrtf(var + LN_EPS);
    float a = pa[0];
    f32x4 o4;
#pragma unroll
    for (int c = 0; c < 4; c++) {
        int col = tid * 4 + c;
        float yv = (v[c] - mean) * rstd * g_ln[col] + b_ln[col];
        o4[c] = (yv >= 0.0f) ? yv : a * yv;
    }
    *(f32x4*)(out + (size_t)row * DIM + tid * 4) = o4;
}

// ---------- launch ----------
extern "C" void kernel_launch(void* const* d_in, const int* in_sizes, int n_in,
                              void* d_out, int out_size, void* d_ws, size_t ws_size,
                              hipStream_t stream) {
    const float* x    = (const float*)d_in[0];
    const float* bw   = (const float*)d_in[1];
    const float* sw   = (const float*)d_in[2];
    const float* ln_g = (const float*)d_in[3];
    const float* ln_b = (const float*)d_in[4];
    const float* pa   = (const float*)d_in[5];
    const float* gridK = (const float*)d_in[6];
    float* out = (float*)d_out;

    const size_t wbytes = (size_t)2 * DIM * KTOT * sizeof(bf16_t);   // 37.75 MB
    // per-slab: A = R*9216*2 B, hbuf = ksplit*R*1024*4 B
    int R = 8192, ksplit = 2;
    for (;;) {
        size_t need = wbytes + (size_t)R * KTOT * 2 + (size_t)ksplit * R * DIM * 4;
        if (need <= ws_size || R == 512) break;
        R >>= 1;
        int mt = R / 256;
        ksplit = (mt >= 32) ? 2 : (mt >= 16) ? 4 : 8;
    }
    int mtiles = R / 256;
    int mshift = 0; while ((1 << mshift) < mtiles) mshift++;
    int mmask = mtiles - 1;
    int grid = mtiles * 4 * ksplit;

    char* wsc = (char*)d_ws;
    bf16_t* Wbuf = (bf16_t*)wsc;
    bf16_t* Abuf = (bf16_t*)(wsc + wbytes);
    float*  hbuf = (float*)(wsc + wbytes + (size_t)R * KTOT * 2);

    pack_w<<<(2 * DIM * DIM) / 256, 256, 0, stream>>>(bw, sw, Wbuf);

    auto launch_gemm = [&](const bf16_t* Wl, hipStream_t st) {
        if (ksplit == 2)
            gemm_ab<144><<<grid, 512, 0, st>>>(Abuf, Wl, hbuf, mmask, mshift, R);
        else if (ksplit == 4)
            gemm_ab<72><<<grid, 512, 0, st>>>(Abuf, Wl, hbuf, mmask, mshift, R);
        else
            gemm_ab<36><<<grid, 512, 0, st>>>(Abuf, Wl, hbuf, mmask, mshift, R);
    };

    const int nslab = BATCH / R;
    for (int sidx = 0; sidx < nslab; sidx++) {
        const size_t row0 = (size_t)sidx * R;
        const float* x0 = x + row0 * DIM;
        // layer 0
        prep_A<<<R, 256, 0, stream>>>(x0, Abuf, gridK);
        launch_gemm(Wbuf, stream);
        ln_mid_A<<<R, 256, 0, stream>>>(hbuf, R, ksplit, ln_g, ln_b, pa,
                                        Abuf, gridK + DIM * NKNOT);
        // layer 1
        launch_gemm(Wbuf + (size_t)DIM * KTOT, stream);
        ln_out<<<R, 256, 0, stream>>>(hbuf, R, ksplit, ln_g + DIM, ln_b + DIM,
                                      pa + 1, out + row0 * DIM);
    }
}

// Round 3
// 566.195 us; speedup vs baseline: 1.0139x; 1.0139x over previous
//
#include <hip/hip_runtime.h>
#include <hip/hip_bf16.h>
#include <cstdint>
#include <cstddef>

// ---------- types ----------
typedef __bf16 bf16_t;
typedef __bf16 bf16x8 __attribute__((ext_vector_type(8)));
typedef __bf16 bf16x4 __attribute__((ext_vector_type(4)));
typedef float  f32x4  __attribute__((ext_vector_type(4)));

#define DIM    1024
#define NCOEF  8
#define KTOT   (DIM + DIM * NCOEF)   // 9216
#define NKNOT  12
#define BATCH  8192
#define LN_EPS 1e-5f

// ---------- device helpers ----------
__device__ __forceinline__ float gelu_exact(float x) {
    return 0.5f * x * (1.0f + erff(x * 0.70710678118654752440f));
}

__device__ __forceinline__ void gl_lds16(const void* g, void* l) {
    __builtin_amdgcn_global_load_lds(
        (const __attribute__((address_space(1))) unsigned int*)(uintptr_t)g,
        (__attribute__((address_space(3))) unsigned int*)(uintptr_t)l, 16, 0, 0);
}

__device__ __forceinline__ uint64_t pack4bf(float a, float b, float c, float d) {
    union { bf16_t h[4]; uint64_t q; } u;
    u.h[0] = (bf16_t)a; u.h[1] = (bf16_t)b; u.h[2] = (bf16_t)c; u.h[3] = (bf16_t)d;
    return u.q;
}

// Uniform cubic B-spline: 8 bf16 bases of one feature as 16 bytes (lo,hi).
__device__ __forceinline__ void spline8(float x, float g0, float invh,
                                        uint64_t& lo, uint64_t& hi) {
    float u = (x - g0) * invh;
    float jf = floorf(u);
    int j = (int)jf;
    float f = u - jf;
    float f2 = f * f, f3 = f2 * f;
    float om = 1.0f - f, om2 = om * om;
    float w0 = om2 * om * (1.0f / 6.0f);
    float w3 = f3 * (1.0f / 6.0f);
    float w1 = fmaf(0.5f, f3, 2.0f / 3.0f) - f2;
    float w2 = 1.0f - w0 - w1 - w3;
    uint64_t W64 = pack4bf(w0, w1, w2, w3);
    if (!(u >= 0.0f && u < 11.0f)) W64 = 0;
    int sh = (j - 3) * 16;
    if (sh >= 0) {
        int s = sh & 63;
        uint64_t loW = W64 << s;
        uint64_t hiW = s ? (W64 >> (64 - s)) : 0ull;
        lo = (sh < 64) ? loW : 0ull;
        hi = (sh < 64) ? hiW : loW;
    } else {
        lo = W64 >> (-sh);
        hi = 0ull;
    }
}

// ---------- W pack: [base_w | spline_w] f32 -> bf16, K-packed ----------
__global__ void pack_w(const float* __restrict__ bw, const float* __restrict__ sw,
                       bf16_t* __restrict__ W) {
    int idx = blockIdx.x * 256 + threadIdx.x;      // (layer,o,j)
    bf16_t* wrow = W + (size_t)(idx >> 10) * KTOT;
    int j = idx & 1023;
    wrow[j] = (bf16_t)bw[idx];
    const float4* sp = (const float4*)(sw + (size_t)idx * NCOEF);
    float4 s0 = sp[0], s1 = sp[1];
    bf16x8 v;
    v[0] = (bf16_t)s0.x; v[1] = (bf16_t)s0.y; v[2] = (bf16_t)s0.z; v[3] = (bf16_t)s0.w;
    v[4] = (bf16_t)s1.x; v[5] = (bf16_t)s1.y; v[6] = (bf16_t)s1.z; v[7] = (bf16_t)s1.w;
    *(bf16x8*)(wrow + DIM + j * NCOEF) = v;
}

// ---------- layer-0 A build: A[row] = [gelu(x) bf16 x1024 | bases bf16 x8192] ----------
__global__ void prep_A(const float* __restrict__ x, bf16_t* __restrict__ A,
                       const float* __restrict__ gp) {
    const int row = blockIdx.x, t = threadIdx.x;   // 256 threads, 4 features each
    const float g0 = gp[0];
    const float invh = 1.0f / (gp[1] - gp[0]);
    f32x4 v = *(const f32x4*)(x + (size_t)row * DIM + t * 4);
    bf16_t* Ar = A + (size_t)row * KTOT;
    bf16x4 ge;
#pragma unroll
    for (int k = 0; k < 4; k++) ge[k] = (bf16_t)gelu_exact(v[k]);
    *(bf16x4*)(Ar + t * 4) = ge;
#pragma unroll
    for (int k = 0; k < 4; k++) {
        uint64_t lo, hi;
        union { uint64_t u[2]; uint4 q; } o;
        spline8(v[k], g0, invh, lo, hi);
        o.u[0] = lo; o.u[1] = hi;
        *(uint4*)(Ar + DIM + (t * 4 + k) * NCOEF) = o.q;
    }
}

// =====================================================================
// Dense GEMM, fine-phase schedule (m201-style port):
// BM=BN=256, BK=32, 8 waves, 4-slot LDS rotation, prefetch depth 3 tiles.
// Per tile: 2 phases; each = {ds_read frags ; stage half ; [gate] ; BAR ;
// lgkmcnt(0) ; setprio(1) 16xMFMA setprio(0) ; BAR}. vmcnt gate once/tile
// = vmcnt(8) steady (2 tiles in flight), 4/0 in tail.
// Slot safety: stage(t+3) -> slot (t-1)&3, last read before tile t-1's
// trailing barrier; stage issued after it. Residency: tile t+1's loads
// (issued in t-2) drained by gate in P1(t) + leading barrier.
// =====================================================================

#define STR2(x) #x
#define GATEV(N) asm volatile("s_waitcnt vmcnt(" STR2(N) ")" ::: "memory");

#define MF_ROW(I, A_) \
    acc[I][0] = __builtin_amdgcn_mfma_f32_16x16x32_bf16(A_, b0, acc[I][0], 0, 0, 0); \
    acc[I][1] = __builtin_amdgcn_mfma_f32_16x16x32_bf16(A_, b1, acc[I][1], 0, 0, 0); \
    acc[I][2] = __builtin_amdgcn_mfma_f32_16x16x32_bf16(A_, b2, acc[I][2], 0, 0, 0); \
    acc[I][3] = __builtin_amdgcn_mfma_f32_16x16x32_bf16(A_, b3, acc[I][3], 0, 0, 0);

#define TILE(T, S, SP, DOSTAGE, GATESTMT) { \
    bf16x8 a0, a1, a2, a3, a4, a5, a6, a7, b0, b1, b2, b3; \
    /* ---- P0: frags (A rows 0-3 + all B) ; stage A(T+3) ---- */ \
    { const bf16_t* Ab_ = ldsA + (S) * 8192 + aOff; \
      const bf16_t* Bb_ = ldsB + (S) * 8192 + bOff; \
      a0 = *(const bf16x8*)(Ab_);        a1 = *(const bf16x8*)(Ab_ + 512); \
      a2 = *(const bf16x8*)(Ab_ + 1024); a3 = *(const bf16x8*)(Ab_ + 1536); \
      b0 = *(const bf16x8*)(Bb_);        b1 = *(const bf16x8*)(Bb_ + 512); \
      b2 = *(const bf16x8*)(Bb_ + 1024); b3 = *(const bf16x8*)(Bb_ + 1536); } \
    if (DOSTAGE) { \
      gl_lds16(Ag0 + (size_t)((T) + 3) * 32, ldsA + (SP) * 8192 + tid * 8); \
      gl_lds16(Ag1 + (size_t)((T) + 3) * 32, ldsA + (SP) * 8192 + 4096 + tid * 8); } \
    __builtin_amdgcn_s_barrier(); \
    asm volatile("s_waitcnt lgkmcnt(0)" ::: "memory"); \
    __builtin_amdgcn_sched_barrier(0); \
    __builtin_amdgcn_s_setprio(1); \
    MF_ROW(0, a0) MF_ROW(1, a1) MF_ROW(2, a2) MF_ROW(3, a3) \
    __builtin_amdgcn_s_setprio(0); \
    __builtin_amdgcn_s_barrier(); \
    /* ---- P1: frags (A rows 4-7) ; stage B(T+3) ; gate ---- */ \
    { const bf16_t* Ab_ = ldsA + (S) * 8192 + aOff; \
      a4 = *(const bf16x8*)(Ab_ + 2048); a5 = *(const bf16x8*)(Ab_ + 2560); \
      a6 = *(const bf16x8*)(Ab_ + 3072); a7 = *(const bf16x8*)(Ab_ + 3584); } \
    if (DOSTAGE) { \
      gl_lds16(Bg0 + (size_t)((T) + 3) * 32, ldsB + (SP) * 8192 + tid * 8); \
      gl_lds16(Bg1 + (size_t)((T) + 3) * 32, ldsB + (SP) * 8192 + 4096 + tid * 8); } \
    GATESTMT \
    __builtin_amdgcn_s_barrier(); \
    asm volatile("s_waitcnt lgkmcnt(0)" ::: "memory"); \
    __builtin_amdgcn_sched_barrier(0); \
    __builtin_amdgcn_s_setprio(1); \
    MF_ROW(4, a4) MF_ROW(5, a5) MF_ROW(6, a6) MF_ROW(7, a7) \
    __builtin_amdgcn_s_setprio(0); \
    __builtin_amdgcn_s_barrier(); \
}

#define PSTAGE(T, S) \
    gl_lds16(Ag0 + (size_t)(T) * 32, ldsA + (S) * 8192 + tid * 8); \
    gl_lds16(Ag1 + (size_t)(T) * 32, ldsA + (S) * 8192 + 4096 + tid * 8); \
    gl_lds16(Bg0 + (size_t)(T) * 32, ldsB + (S) * 8192 + tid * 8); \
    gl_lds16(Bg1 + (size_t)(T) * 32, ldsB + (S) * 8192 + 4096 + tid * 8);

template<int NTK>
__global__ __launch_bounds__(512, 2) void gemm_ab(
    const bf16_t* __restrict__ A,      // [rows, 9216] bf16
    const bf16_t* __restrict__ W,      // [1024, 9216] bf16
    float* __restrict__ C,             // [ksplit, rows, 1024] f32 partials
    int mmask, int mshift, int rows) {
    __shared__ __align__(16) bf16_t lds[65536];    // 128 KB
    bf16_t* __restrict__ ldsA = lds;
    bf16_t* __restrict__ ldsB = lds + 32768;

    const int tid = threadIdx.x;
    const int l = tid & 63, wv = tid >> 6;
    const int wm = wv >> 2, wn = wv & 3;           // 2M x 4N waves, 128x64 each

    // XCD-aware swizzle (grid always divisible by 8)
    const int chunk = gridDim.x >> 3;
    const int bid = blockIdx.x;
    const int wg = (bid & 7) * chunk + (bid >> 3);
    const int bm = wg & mmask;
    const int bn = (wg >> mshift) & 3;
    const int ks = wg >> (mshift + 2);
    const int row0 = bm << 8, col0 = bn << 8;
    const int koff0 = ks * (NTK * 32);

    // staging: thread covers rows srow, srow+128; source pre-swizzled by chunk
    const int srow = tid >> 2;
    const int slc = (tid & 3) ^ ((srow >> 1) & 3);
    const bf16_t* __restrict__ Ag0 = A + (size_t)(row0 + srow) * KTOT + koff0 + slc * 8;
    const bf16_t* __restrict__ Ag1 = Ag0 + (size_t)128 * KTOT;
    const bf16_t* __restrict__ Bg0 = W + (size_t)(col0 + srow) * KTOT + koff0 + slc * 8;
    const bf16_t* __restrict__ Bg1 = Bg0 + (size_t)128 * KTOT;

    // fragment-read offsets; physical chunk = logical(l>>4) ^ ((row>>1)&3)
    const int l15 = l & 15;
    const int pc = (l >> 4) ^ ((l15 >> 1) & 3);
    const int aOff = (wm * 128 + l15) * 32 + pc * 8;
    const int bOff = (wn * 64 + l15) * 32 + pc * 8;

    f32x4 acc[8][4] = {};

    // prologue: tiles 0,1,2 staged (12 loads); gate tile 0 resident
    PSTAGE(0, 0)
    PSTAGE(1, 1)
    PSTAGE(2, 2)
    GATEV(8)
    __builtin_amdgcn_s_barrier();

#pragma unroll 1
    for (int t = 0; t < NTK - 4; t += 4) {
        TILE(t + 0, 0, 3, 1, GATEV(8))
        TILE(t + 1, 1, 0, 1, GATEV(8))
        TILE(t + 2, 2, 1, 1, GATEV(8))
        TILE(t + 3, 3, 2, 1, GATEV(8))
    }
    TILE(NTK - 4, 0, 3, 1, GATEV(8))
    TILE(NTK - 3, 1, 0, 0, GATEV(4))
    TILE(NTK - 2, 2, 0, 0, GATEV(0))
    TILE(NTK - 1, 3, 0, 0, ;)

    float* __restrict__ Cp = C + (size_t)ks * rows * DIM;
    const int r0 = row0 + wm * 128 + (l >> 4) * 4;
    const int c0 = col0 + wn * 64 + l15;
#pragma unroll
    for (int i = 0; i < 8; i++)
#pragma unroll
        for (int j = 0; j < 4; j++)
#pragma unroll
            for (int r = 0; r < 4; r++)
                Cp[(size_t)(r0 + i * 16 + r) * DIM + c0 + j * 16] = acc[i][j][r];
}

// ---------- LN + PReLU over summed partials -> next-layer A (gelu + bases) ----------
__global__ void ln_mid_A(const float* __restrict__ h, int rows, int ksplit,
                         const float* __restrict__ g_ln, const float* __restrict__ b_ln,
                         const float* __restrict__ pa, bf16_t* __restrict__ A,
                         const float* __restrict__ gp) {
    const int row = blockIdx.x, tid = threadIdx.x;
    const int w = tid >> 6, l = tid & 63;
    f32x4 v = {0.0f, 0.0f, 0.0f, 0.0f};
    for (int ks = 0; ks < ksplit; ks++)
        v += *(const f32x4*)(h + ((size_t)ks * rows + row) * DIM + tid * 4);
    float s = v[0] + v[1] + v[2] + v[3];
    float q = v[0] * v[0] + v[1] * v[1] + v[2] * v[2] + v[3] * v[3];
#pragma unroll
    for (int o = 32; o > 0; o >>= 1) { s += __shfl_xor(s, o); q += __shfl_xor(q, o); }
    __shared__ float rs[4], rq[4];
    if (l == 0) { rs[w] = s; rq[w] = q; }
    __syncthreads();
    s = rs[0] + rs[1] + rs[2] + rs[3];
    q = rq[0] + rq[1] + rq[2] + rq[3];
    float mean = s * (1.0f / DIM);
    float var = q * (1.0f / DIM) - mean * mean;
    float rstd = rsqrtf(var + LN_EPS);
    float a = pa[0];
    const float g0 = gp[0];
    const float invh = 1.0f / (gp[1] - gp[0]);
    bf16_t* Ar = A + (size_t)row * KTOT;
    bf16x4 ge;
#pragma unroll
    for (int c = 0; c < 4; c++) {
        int col = tid * 4 + c;
        float yv = (v[c] - mean) * rstd * g_ln[col] + b_ln[col];
        yv = (yv >= 0.0f) ? yv : a * yv;
        ge[c] = (bf16_t)gelu_exact(yv);
        uint64_t lo, hi;
        union { uint64_t u[2]; uint4 qv; } o;
        spline8(yv, g0, invh, lo, hi);
        o.u[0] = lo; o.u[1] = hi;
        *(uint4*)(Ar + DIM + (size_t)col * NCOEF) = o.qv;
    }
    *(bf16x4*)(Ar + tid * 4) = ge;
}

// ---------- final LN + PReLU -> f32 out ----------
__global__ void ln_out(const float* __restrict__ h, int rows, int ksplit,
                       const float* __restrict__ g_ln, const float* __restrict__ b_ln,
                       const float* __restrict__ pa, float* __restrict__ out) {
    const int row = blockIdx.x, tid = threadIdx.x;
    const int w = tid >> 6, l = tid & 63;
    f32x4 v = {0.0f, 0.0f, 0.0f, 0.0f};
    for (int ks = 0; ks < ksplit; ks++)
        v += *(const f32x4*)(h + ((size_t)ks * rows + row) * DIM + tid * 4);
    float s = v[0] + v[1] + v[2] + v[3];
    float q = v[0] * v[0] + v[1] * v[1] + v[2] * v[2] + v[3] * v[3];
#pragma unroll
    for (int o = 32; o > 0; o >>= 1) { s += __shfl_xor(s, o); q += __shfl_xor(q, o); }
    __shared__ float rs[4], rq[4];
    if (l == 0) { rs[w] = s; rq[w] = q; }
    __syncthreads();
    s = rs[0] + rs[1] + rs[2] + rs[3];
    q = rq[0] + rq[1] + rq[2] + rq[3];
    float mean = s * (1.0f / DIM);
    float var = q * (1.0f / DIM) - mean * mean;
    float rstd = rsqrtf(var + LN_EPS);
    float a = pa[0];
    f32x4 o4;
#pragma unroll
    for (int c = 0; c < 4; c++) {
        int col = tid * 4 + c;
        float yv = (v[c] - mean) * rstd * g_ln[col] + b_ln[col];
        o4[c] = (yv >= 0.0f) ? yv : a * yv;
    }
    *(f32x4*)(out + (size_t)row * DIM + tid * 4) = o4;
}

// ---------- launch ----------
extern "C" void kernel_launch(void* const* d_in, const int* in_sizes, int n_in,
                              void* d_out, int out_size, void* d_ws, size_t ws_size,
                              hipStream_t stream) {
    const float* x    = (const float*)d_in[0];
    const float* bw   = (const float*)d_in[1];
    const float* sw   = (const float*)d_in[2];
    const float* ln_g = (const float*)d_in[3];
    const float* ln_b = (const float*)d_in[4];
    const float* pa   = (const float*)d_in[5];
    const float* gridK = (const float*)d_in[6];
    float* out = (float*)d_out;

    const size_t wbytes = (size_t)2 * DIM * KTOT * sizeof(bf16_t);   // 37.75 MB
    // per-slab: A = R*9216*2 B, hbuf = ksplit*R*1024*4 B
    int R = 8192, ksplit = 2;
    for (;;) {
        size_t need = wbytes + (size_t)R * KTOT * 2 + (size_t)ksplit * R * DIM * 4;
        if (need <= ws_size || R == 512) break;
        R >>= 1;
        int mt = R / 256;
        ksplit = (mt >= 32) ? 2 : (mt >= 16) ? 4 : 8;
    }
    int mtiles = R / 256;
    int mshift = 0; while ((1 << mshift) < mtiles) mshift++;
    int mmask = mtiles - 1;
    int grid = mtiles * 4 * ksplit;

    char* wsc = (char*)d_ws;
    bf16_t* Wbuf = (bf16_t*)wsc;
    bf16_t* Abuf = (bf16_t*)(wsc + wbytes);
    float*  hbuf = (float*)(wsc + wbytes + (size_t)R * KTOT * 2);

    pack_w<<<(2 * DIM * DIM) / 256, 256, 0, stream>>>(bw, sw, Wbuf);

    auto launch_gemm = [&](const bf16_t* Wl, hipStream_t st) {
        if (ksplit == 2)
            gemm_ab<144><<<grid, 512, 0, st>>>(Abuf, Wl, hbuf, mmask, mshift, R);
        else if (ksplit == 4)
            gemm_ab<72><<<grid, 512, 0, st>>>(Abuf, Wl, hbuf, mmask, mshift, R);
        else
            gemm_ab<36><<<grid, 512, 0, st>>>(Abuf, Wl, hbuf, mmask, mshift, R);
    };

    const int nslab = BATCH / R;
    for (int sidx = 0; sidx < nslab; sidx++) {
        const size_t row0 = (size_t)sidx * R;
        const float* x0 = x + row0 * DIM;
        // layer 0
        prep_A<<<R, 256, 0, stream>>>(x0, Abuf, gridK);
        launch_gemm(Wbuf, stream);
        ln_mid_A<<<R, 256, 0, stream>>>(hbuf, R, ksplit, ln_g, ln_b, pa,
                                        Abuf, gridK + DIM * NKNOT);
        // layer 1
        launch_gemm(Wbuf + (size_t)DIM * KTOT, stream);
        ln_out<<<R, 256, 0, stream>>>(hbuf, R, ksplit, ln_g + DIM, ln_b + DIM,
                                      pa + 1, out + row0 * DIM);
    }
}